// Round 17
// baseline (96.259 us; speedup 1.0000x reference)
//
#include <hip/hip_runtime.h>
#include <stdint.h>

#define BATCH   16384
#define NUM_NUM 32
#define NUM_CAT 32
#define CARD    128
#define OUT_F   32
#define XSTRIDE 4128   // NUM_NUM + NUM_CAT*CARD
#define OSTRIDE 1056   // NUM_NUM + NUM_CAT*OUT_F

typedef __attribute__((ext_vector_type(8))) short short8;  // 8 bf16 (4 VGPRs)
typedef __attribute__((ext_vector_type(4))) float f32x4;

// f32 -> bf16 RNE (r15-proven, absmax 0.031 vs 0.116 threshold).
__device__ __forceinline__ unsigned short f2bf(float f) {
    unsigned u = __builtin_bit_cast(unsigned, f);
    return (unsigned short)((u + 0x7FFFu + ((u >> 16) & 1u)) >> 16);
}

// r15 MFMA formulation + FEATURE-PAIR blocks for 1KB DRAM chunks.
// Granule evidence: 32B=2.1, 128B=3.9, 512B=4.36 TB/s (r5/r6/r15); within a row
// the f,f+1 slices are CONTIGUOUS 1KB -> a wave issues all 16 row-loads (2x8
// float4) in one window, doubling per-page service vs r15.
// Block = (pair p, 128 rows); wave = (row-half, n-half): rhalf=wv&1, nh=wv>>1.
// Per wave: bw[2][4] (2 f x 4 kf, one n-half) = 32 VGPR; acc 8; staging 16
// float4 = 64 (both f's in flight together - the point); peak ~118 < 128 cap.
// Fragments (HW-verified m89/m91): A lane l = A[row=l&15][k=(l>>4)*8+i];
// B lane l = B[k][col=l&15]; D col=l&15, row=(l>>4)*4+reg. No LDS, no barriers.
// Spill signature = WRITE_SIZE >> 68MB (r4); neutral result = roofline, stop.
__global__ __launch_bounds__(256, 4) void emb_pair(const float* __restrict__ x,
                                                   const float* __restrict__ Wm,
                                                   const float* __restrict__ bias,
                                                   float* __restrict__ out) {
    const int p     = blockIdx.x;          // feature pair 0..15
    const int row0  = blockIdx.y * 128;
    const int tid   = threadIdx.x;
    const int l     = tid & 63;
    const int wv    = tid >> 6;
    const int rhalf = wv & 1;    // which 64-row half
    const int nh    = wv >> 1;   // which 16-col output half
    const int lr    = l & 15;    // A-row / B-col / D-col
    const int lg    = l >> 4;    // k-group (8 elems each)

    // ---- B fragments: W[2p+ff] -> bf16 VGPRs, one n-half, 4 k-frags each ----
    short8 bw[2][4];
#pragma unroll
    for (int ff = 0; ff < 2; ++ff) {
        const float* wf = Wm + (size_t)(p * 2 + ff) * (CARD * OUT_F);
#pragma unroll
        for (int kf = 0; kf < 4; ++kf)
#pragma unroll
            for (int i = 0; i < 8; ++i)
                bw[ff][kf][i] =
                    (short)f2bf(wf[(kf * 32 + lg * 8 + i) * OUT_F + nh * 16 + lr]);
    }

    const float bias0 = bias[(p * 2 + 0) * OUT_F + nh * 16 + lr];
    const float bias1 = bias[(p * 2 + 1) * OUT_F + nh * 16 + lr];

    const float* xp    = x + NUM_NUM + p * 256;            // pair's 1KB row-slice base
    float*       obase = out + NUM_NUM + p * 2 * OUT_F + nh * 16;
    const int    wrow  = row0 + rhalf * 64;

#pragma unroll
    for (int m = 0; m < 4; ++m) {
        const float* xr = xp + (size_t)(wrow + m * 16 + lr) * XSTRIDE;

        // all 16 loads issued together: the wave covers 16 rows x 1KB contiguous
        float4 v0[8], v1[8];
#pragma unroll
        for (int kf = 0; kf < 4; ++kf) {
            v0[kf * 2]     = *(const float4*)(xr + kf * 32 + lg * 8);
            v0[kf * 2 + 1] = *(const float4*)(xr + kf * 32 + lg * 8 + 4);
        }
#pragma unroll
        for (int kf = 0; kf < 4; ++kf) {
            v1[kf * 2]     = *(const float4*)(xr + 128 + kf * 32 + lg * 8);
            v1[kf * 2 + 1] = *(const float4*)(xr + 128 + kf * 32 + lg * 8 + 4);
        }

        f32x4 acc0 = {0.f, 0.f, 0.f, 0.f};
        f32x4 acc1 = {0.f, 0.f, 0.f, 0.f};
#pragma unroll
        for (int kf = 0; kf < 4; ++kf) {
            short8 af;
            af[0] = (short)f2bf(v0[kf * 2].x);     af[1] = (short)f2bf(v0[kf * 2].y);
            af[2] = (short)f2bf(v0[kf * 2].z);     af[3] = (short)f2bf(v0[kf * 2].w);
            af[4] = (short)f2bf(v0[kf * 2 + 1].x); af[5] = (short)f2bf(v0[kf * 2 + 1].y);
            af[6] = (short)f2bf(v0[kf * 2 + 1].z); af[7] = (short)f2bf(v0[kf * 2 + 1].w);
            acc0 = __builtin_amdgcn_mfma_f32_16x16x32_bf16(af, bw[0][kf], acc0, 0, 0, 0);
        }
#pragma unroll
        for (int kf = 0; kf < 4; ++kf) {
            short8 af;
            af[0] = (short)f2bf(v1[kf * 2].x);     af[1] = (short)f2bf(v1[kf * 2].y);
            af[2] = (short)f2bf(v1[kf * 2].z);     af[3] = (short)f2bf(v1[kf * 2].w);
            af[4] = (short)f2bf(v1[kf * 2 + 1].x); af[5] = (short)f2bf(v1[kf * 2 + 1].y);
            af[6] = (short)f2bf(v1[kf * 2 + 1].z); af[7] = (short)f2bf(v1[kf * 2 + 1].w);
            acc1 = __builtin_amdgcn_mfma_f32_16x16x32_bf16(af, bw[1][kf], acc1, 0, 0, 0);
        }

        // D: row = (l>>4)*4 + r, col = lr; two 64B segments per row (f0, f1)
#pragma unroll
        for (int r = 0; r < 4; ++r) {
            const size_t orow = (size_t)(wrow + m * 16 + lg * 4 + r) * OSTRIDE;
            obase[orow + lr]          = acc0[r] + bias0;
            obase[orow + OUT_F + lr]  = acc1[r] + bias1;
        }
    }

    // ---- numeric passthrough: pair p == (stripe & 15) copies its 128 rows ----
    if (p == (blockIdx.y & 15)) {
        const int r    = tid >> 1;            // 0..127
        const int half = (tid & 1) * 16;      // 16 floats = 4 float4
        const float4* src = (const float4*)(x + (size_t)(row0 + r) * XSTRIDE + half);
        float4*       dst = (float4*)(out + (size_t)(row0 + r) * OSTRIDE + half);
#pragma unroll
        for (int q = 0; q < 4; ++q) dst[q] = src[q];
    }
}

extern "C" void kernel_launch(void* const* d_in, const int* in_sizes, int n_in,
                              void* d_out, int out_size, void* d_ws, size_t ws_size,
                              hipStream_t stream) {
    const float* x    = (const float*)d_in[0];
    const float* W    = (const float*)d_in[1];
    const float* bias = (const float*)d_in[2];
    float*       out  = (float*)d_out;

    dim3 grid(NUM_CAT / 2, BATCH / 128);  // (16, 128), pair fastest
    emb_pair<<<grid, 256, 0, stream>>>(x, W, bias, out);
}

// Round 18
// 86.407 us; speedup vs baseline: 1.1140x; 1.1140x over previous
//
#include <hip/hip_runtime.h>
#include <stdint.h>

#define BATCH   16384
#define NUM_NUM 32
#define NUM_CAT 32
#define CARD    128
#define OUT_F   32
#define XSTRIDE 4128   // NUM_NUM + NUM_CAT*CARD
#define OSTRIDE 1056   // NUM_NUM + NUM_CAT*OUT_F

typedef __attribute__((ext_vector_type(8))) short short8;  // 8 bf16 (4 VGPRs)
typedef __attribute__((ext_vector_type(4))) float f32x4;

// f32 -> bf16, round-to-nearest-even, pure bit ops (r15-proven, absmax 0.031).
__device__ __forceinline__ unsigned short f2bf(float f) {
    unsigned u = __builtin_bit_cast(unsigned, f);
    return (unsigned short)((u + 0x7FFFu + ((u >> 16) & 1u)) >> 16);
}

// r15 VERBATIM (proven 78.1us) with launch_bounds(256,5): 5 blocks/CU = 20
// waves/CU (was 16), VGPR cap 102 vs live set ~90-100 -> +25% independent
// latency-coverage agents on the scattered-512B-chunk stream. r16 (explicit
// ILP) and r17 (1KB granule) both failed to beat 78 -> latency coverage is
// the last lever on this structure. Spill signature = WRITE_SIZE >> 68MB.
// MFMA formulation: per f, C(16384x32) = A(16384x128)*B(128x32), bf16/f32acc.
// Block = (f, 256 rows); wave owns 64 rows = 4 M-tiles. NO LDS, NO barriers.
// Fragments (HW-verified m89/m91): A lane l = A[row=l&15][k=(l>>4)*8+i];
// B lane l = B[k=(l>>4)*8+i][col=l&15]; D col=l&15, row=(l>>4)*4+reg.
__global__ __launch_bounds__(256, 5) void emb_mfma(const float* __restrict__ x,
                                                   const float* __restrict__ Wm,
                                                   const float* __restrict__ bias,
                                                   float* __restrict__ out) {
    const int f    = blockIdx.x;
    const int row0 = blockIdx.y * 256;
    const int tid  = threadIdx.x;
    const int l    = tid & 63;
    const int wv   = tid >> 6;
    const int lr   = l & 15;   // A-row / B-col / D-col
    const int lg   = l >> 4;   // k-group (8 elems each)

    // ---- B fragments: W[f] -> bf16 VGPRs, 2 n-tiles x 4 k-frags (one-time) ----
    const float* wf = Wm + (size_t)f * (CARD * OUT_F);
    short8 bw[2][4];
#pragma unroll
    for (int n = 0; n < 2; ++n)
#pragma unroll
        for (int kf = 0; kf < 4; ++kf)
#pragma unroll
            for (int i = 0; i < 8; ++i)
                bw[n][kf][i] = (short)f2bf(wf[(kf * 32 + lg * 8 + i) * OUT_F + n * 16 + lr]);

    const float bias0 = bias[f * OUT_F + lr];
    const float bias1 = bias[f * OUT_F + 16 + lr];

    const float* xf    = x + NUM_NUM + f * CARD;
    float*       obase = out + NUM_NUM + f * OUT_F;

#pragma unroll
    for (int m = 0; m < 4; ++m) {
        const int    mrow = row0 + wv * 64 + m * 16 + lr;
        const float* xr   = xf + (size_t)mrow * XSTRIDE;

        f32x4 acc0 = {0.f, 0.f, 0.f, 0.f};
        f32x4 acc1 = {0.f, 0.f, 0.f, 0.f};
#pragma unroll
        for (int kf = 0; kf < 4; ++kf) {
            const float4 v0 = *(const float4*)(xr + kf * 32 + lg * 8);
            const float4 v1 = *(const float4*)(xr + kf * 32 + lg * 8 + 4);
            short8 af;
            af[0] = (short)f2bf(v0.x); af[1] = (short)f2bf(v0.y);
            af[2] = (short)f2bf(v0.z); af[3] = (short)f2bf(v0.w);
            af[4] = (short)f2bf(v1.x); af[5] = (short)f2bf(v1.y);
            af[6] = (short)f2bf(v1.z); af[7] = (short)f2bf(v1.w);
            acc0 = __builtin_amdgcn_mfma_f32_16x16x32_bf16(af, bw[0][kf], acc0, 0, 0, 0);
            acc1 = __builtin_amdgcn_mfma_f32_16x16x32_bf16(af, bw[1][kf], acc1, 0, 0, 0);
        }

        // D: row = (l>>4)*4 + r, col = lr. Per instr: 4 rows x 64B segments;
        // acc0/acc1 halves of each row's 128B line merge in L2.
#pragma unroll
        for (int r = 0; r < 4; ++r) {
            const size_t orow = (size_t)(row0 + wv * 64 + m * 16 + lg * 4 + r) * OSTRIDE;
            obase[orow + lr]      = acc0[r] + bias0;
            obase[orow + 16 + lr] = acc1[r] + bias1;
        }
    }

    // ---- numeric passthrough: one block per stripe (f == stripe&31), row/thread ----
    if (f == (blockIdx.y & 31)) {
        const float4* src = (const float4*)(x + (size_t)(row0 + tid) * XSTRIDE);
        float4*       dst = (float4*)(out + (size_t)(row0 + tid) * OSTRIDE);
#pragma unroll
        for (int q = 0; q < 8; ++q) dst[q] = src[q];
    }
}

extern "C" void kernel_launch(void* const* d_in, const int* in_sizes, int n_in,
                              void* d_out, int out_size, void* d_ws, size_t ws_size,
                              hipStream_t stream) {
    const float* x    = (const float*)d_in[0];
    const float* W    = (const float*)d_in[1];
    const float* bias = (const float*)d_in[2];
    float*       out  = (float*)d_out;

    dim3 grid(NUM_CAT, BATCH / 256);  // (32, 64), f fastest
    emb_mfma<<<grid, 256, 0, stream>>>(x, W, bias, out);
}

// Round 19
// 78.042 us; speedup vs baseline: 1.2334x; 1.1072x over previous
//
#include <hip/hip_runtime.h>
#include <stdint.h>

#define BATCH   16384
#define NUM_NUM 32
#define NUM_CAT 32
#define CARD    128
#define OUT_F   32
#define XSTRIDE 4128   // NUM_NUM + NUM_CAT*CARD
#define OSTRIDE 1056   // NUM_NUM + NUM_CAT*OUT_F

typedef __attribute__((ext_vector_type(8))) short short8;  // 8 bf16 (4 VGPRs)
typedef __attribute__((ext_vector_type(4))) float f32x4;

// f32 -> bf16, round-to-nearest-even, pure bit ops (r15-proven, absmax 0.031).
__device__ __forceinline__ unsigned short f2bf(float f) {
    unsigned u = __builtin_bit_cast(unsigned, f);
    return (unsigned short)((u + 0x7FFFu + ((u >> 16) & 1u)) >> 16);
}

// FINAL: r15 verbatim (best measured, 78.1us). Session sweep around this point:
// r16 explicit ILP = 80.1; r17 1KB-granule pairs = 96.3 (VGPR-confounded);
// r18 occupancy 5/CU (cap 102) = 86.4. All neighbors worse -> operating point.
// MFMA formulation: per f, C(16384x32) = A(16384x128)*B(128x32), bf16 in /
// f32 acc. Block = (f, 256 rows); wave owns 64 rows = 4 M-tiles of 16.
// NO LDS, NO barriers, W in VGPRs (one-time L2-hot loads). VALU floor gone;
// kernel is a pure streaming loader feeding the matrix pipe at ~4.4 TB/s
// effective (scattered 512B chunks at 16.5KB stride; pure-copy ceiling 6.3).
// Fragments (HW-verified m89/m91): A lane l = A[row=l&15][k=(l>>4)*8+i];
// B lane l = B[k=(l>>4)*8+i][col=l&15]; D col=l&15, row=(l>>4)*4+reg.
// Accuracy: bf16 RNE, 128-term f32-accumulated dots -> absmax 0.031 vs 0.116.
__global__ __launch_bounds__(256, 4) void emb_mfma(const float* __restrict__ x,
                                                   const float* __restrict__ Wm,
                                                   const float* __restrict__ bias,
                                                   float* __restrict__ out) {
    const int f    = blockIdx.x;
    const int row0 = blockIdx.y * 256;
    const int tid  = threadIdx.x;
    const int l    = tid & 63;
    const int wv   = tid >> 6;
    const int lr   = l & 15;   // A-row / B-col / D-col
    const int lg   = l >> 4;   // k-group (8 elems each)

    // ---- B fragments: W[f] -> bf16 VGPRs, 2 n-tiles x 4 k-frags (one-time) ----
    const float* wf = Wm + (size_t)f * (CARD * OUT_F);
    short8 bw[2][4];
#pragma unroll
    for (int n = 0; n < 2; ++n)
#pragma unroll
        for (int kf = 0; kf < 4; ++kf)
#pragma unroll
            for (int i = 0; i < 8; ++i)
                bw[n][kf][i] = (short)f2bf(wf[(kf * 32 + lg * 8 + i) * OUT_F + n * 16 + lr]);

    const float bias0 = bias[f * OUT_F + lr];
    const float bias1 = bias[f * OUT_F + 16 + lr];

    const float* xf    = x + NUM_NUM + f * CARD;
    float*       obase = out + NUM_NUM + f * OUT_F;

#pragma unroll
    for (int m = 0; m < 4; ++m) {
        const int    mrow = row0 + wv * 64 + m * 16 + lr;
        const float* xr   = xf + (size_t)mrow * XSTRIDE;

        f32x4 acc0 = {0.f, 0.f, 0.f, 0.f};
        f32x4 acc1 = {0.f, 0.f, 0.f, 0.f};
#pragma unroll
        for (int kf = 0; kf < 4; ++kf) {
            const float4 v0 = *(const float4*)(xr + kf * 32 + lg * 8);
            const float4 v1 = *(const float4*)(xr + kf * 32 + lg * 8 + 4);
            short8 af;
            af[0] = (short)f2bf(v0.x); af[1] = (short)f2bf(v0.y);
            af[2] = (short)f2bf(v0.z); af[3] = (short)f2bf(v0.w);
            af[4] = (short)f2bf(v1.x); af[5] = (short)f2bf(v1.y);
            af[6] = (short)f2bf(v1.z); af[7] = (short)f2bf(v1.w);
            acc0 = __builtin_amdgcn_mfma_f32_16x16x32_bf16(af, bw[0][kf], acc0, 0, 0, 0);
            acc1 = __builtin_amdgcn_mfma_f32_16x16x32_bf16(af, bw[1][kf], acc1, 0, 0, 0);
        }

        // D: row = (l>>4)*4 + r, col = lr. Per instr: 4 rows x 64B segments;
        // acc0/acc1 halves of each row's 128B line merge in L2.
#pragma unroll
        for (int r = 0; r < 4; ++r) {
            const size_t orow = (size_t)(row0 + wv * 64 + m * 16 + lg * 4 + r) * OSTRIDE;
            obase[orow + lr]      = acc0[r] + bias0;
            obase[orow + 16 + lr] = acc1[r] + bias1;
        }
    }

    // ---- numeric passthrough: one block per stripe (f == stripe&31), row/thread ----
    if (f == (blockIdx.y & 31)) {
        const float4* src = (const float4*)(x + (size_t)(row0 + tid) * XSTRIDE);
        float4*       dst = (float4*)(out + (size_t)(row0 + tid) * OSTRIDE);
#pragma unroll
        for (int q = 0; q < 8; ++q) dst[q] = src[q];
    }
}

extern "C" void kernel_launch(void* const* d_in, const int* in_sizes, int n_in,
                              void* d_out, int out_size, void* d_ws, size_t ws_size,
                              hipStream_t stream) {
    const float* x    = (const float*)d_in[0];
    const float* W    = (const float*)d_in[1];
    const float* bias = (const float*)d_in[2];
    float*       out  = (float*)d_out;

    dim3 grid(NUM_CAT, BATCH / 256);  // (32, 64), f fastest
    emb_mfma<<<grid, 256, 0, stream>>>(x, W, bias, out);
}